// Round 1
// baseline (558.735 us; speedup 1.0000x reference)
//
#include <hip/hip_runtime.h>
#include <hip/hip_bf16.h>

typedef __bf16 bf16_t;
typedef __bf16 bf16x8 __attribute__((ext_vector_type(8)));
typedef float  f32x4  __attribute__((ext_vector_type(4)));

#define DK 1024   // d_in  (K)
#define DN 1024   // d_out (N)
#define RNK 32
#define BM 128
#define BN 128
#define BK 64
#define NKT (DK / BK)   // 16 K-tiles

// ---------------- Pass 1: W_eff = W + C @ V_r^T, stored bf16 ----------------
// grid (8, 16): x -> d-chunk of 128, y -> o-chunk of 64. 128 threads.
__global__ void weff_kernel(const float* __restrict__ W,
                            const float* __restrict__ Vr,
                            const float* __restrict__ C,
                            bf16_t* __restrict__ Weff)
{
    const int d  = blockIdx.x * 128 + threadIdx.x;
    const int o0 = blockIdx.y * 64;
    float vr[RNK];
#pragma unroll
    for (int r = 0; r < RNK; ++r) vr[r] = Vr[d * RNK + r];
    for (int o = o0; o < o0 + 64; ++o) {
        float acc = W[(size_t)o * DK + d];
#pragma unroll
        for (int r = 0; r < RNK; ++r) acc += C[o * RNK + r] * vr[r];
        Weff[(size_t)o * DK + d] = (bf16_t)acc;
    }
}

// ---------------- Pass 2: out[m][n] = sum_k x[m][k]*Weff[n][k] + b[n] -------
// 128x128 tile, BK=64, 256 threads = 4 waves in 2x2, each wave 64x64 via
// 4x4 grid of 16x16x32 bf16 MFMA fragments. Reg-staged global->LDS with
// fp32->bf16 conversion for A; XOR swizzle (row&7)<<4 on 128B LDS rows.
__global__ __launch_bounds__(256, 2) void corrlin_gemm_kernel(
    const float* __restrict__ X, const bf16_t* __restrict__ Weff,
    const float* __restrict__ bias, float* __restrict__ Out)
{
    __shared__ __align__(16) bf16_t Alds[BM * BK]; // 16 KB
    __shared__ __align__(16) bf16_t Blds[BN * BK]; // 16 KB

    const int tid = threadIdx.x;
    const int nwg = gridDim.x;
    const int b0  = blockIdx.x;
    // XCD-bijective swizzle: XCD = b0 % 8 (hw round-robin); give each XCD a
    // contiguous logical range so the 8 bn-blocks of one x-panel share one L2.
    const int L  = (b0 & 7) * (nwg >> 3) + (b0 >> 3);
    const int bm = L >> 3;          // N/BN == 8
    const int bn = L & 7;
    const int m0 = bm * BM;
    const int n0 = bn * BN;

    const int lane = tid & 63;
    const int wid  = tid >> 6;
    const int wm   = wid >> 1;      // 0..1
    const int wn   = wid & 1;       // 0..1

    // staging decomposition: 1024 16B-segments per tile-side, 4 per thread
    const int srow = tid >> 3;      // 0..31
    const int sseg = tid & 7;       // 0..7 (8-float segment within row)

    f32x4 acc[4][4] = {};

    f32x4 a_reg[4][2];
    uint4 b_reg[4];

    auto load_tiles = [&](int kt) {
#pragma unroll
        for (int i = 0; i < 4; ++i) {
            const int row = i * 32 + srow;
            const float* pa = X + (size_t)(m0 + row) * DK + kt * BK + sseg * 8;
            a_reg[i][0] = *(const f32x4*)pa;
            a_reg[i][1] = *(const f32x4*)(pa + 4);
            const bf16_t* pb = Weff + (size_t)(n0 + row) * DK + kt * BK + sseg * 8;
            b_reg[i] = *(const uint4*)pb;
        }
    };

    auto store_tiles = [&]() {
#pragma unroll
        for (int i = 0; i < 4; ++i) {
            const int row = i * 32 + srow;
            const int off = row * (BK * 2) + ((sseg * 16) ^ ((row & 7) << 4));
            bf16x8 av;
#pragma unroll
            for (int j = 0; j < 4; ++j) av[j] = (bf16_t)a_reg[i][0][j];
#pragma unroll
            for (int j = 0; j < 4; ++j) av[4 + j] = (bf16_t)a_reg[i][1][j];
            *(bf16x8*)((char*)Alds + off) = av;
            *(uint4*)((char*)Blds + off) = b_reg[i];
        }
    };

    auto compute_tile = [&]() {
#pragma unroll
        for (int ks = 0; ks < 2; ++ks) {
            bf16x8 af[4], bfr[4];
            const int kb = ks * 64 + (lane >> 4) * 16;  // byte offset along K
#pragma unroll
            for (int mf = 0; mf < 4; ++mf) {
                const int row = wm * 64 + mf * 16 + (lane & 15);
                const int off = row * (BK * 2) + (kb ^ ((row & 7) << 4));
                af[mf] = *(const bf16x8*)((const char*)Alds + off);
            }
#pragma unroll
            for (int nf = 0; nf < 4; ++nf) {
                const int row = wn * 64 + nf * 16 + (lane & 15);
                const int off = row * (BK * 2) + (kb ^ ((row & 7) << 4));
                bfr[nf] = *(const bf16x8*)((const char*)Blds + off);
            }
#pragma unroll
            for (int mf = 0; mf < 4; ++mf)
#pragma unroll
                for (int nf = 0; nf < 4; ++nf)
                    acc[mf][nf] = __builtin_amdgcn_mfma_f32_16x16x32_bf16(
                        af[mf], bfr[nf], acc[mf][nf], 0, 0, 0);
        }
    };

    load_tiles(0);
    store_tiles();
    __syncthreads();
    for (int kt = 0; kt + 1 < NKT; ++kt) {
        load_tiles(kt + 1);   // issue next-tile globals early (latency hides
        compute_tile();       // under this tile's ds_read+MFMA)
        __syncthreads();      // all waves done reading LDS
        store_tiles();        // vmcnt drain happens here, then ds_write
        __syncthreads();
    }
    compute_tile();

    // epilogue: D col = lane&15, row = (lane>>4)*4 + j  [m89-verified]
    const int mbase = m0 + wm * 64;
    const int nbase = n0 + wn * 64;
    float bv[4];
#pragma unroll
    for (int nf = 0; nf < 4; ++nf) bv[nf] = bias[nbase + nf * 16 + (lane & 15)];
#pragma unroll
    for (int mf = 0; mf < 4; ++mf) {
#pragma unroll
        for (int j = 0; j < 4; ++j) {
            const int rm = mbase + mf * 16 + (lane >> 4) * 4 + j;
#pragma unroll
            for (int nf = 0; nf < 4; ++nf) {
                const int cn = nbase + nf * 16 + (lane & 15);
                Out[(size_t)rm * DN + cn] = acc[mf][nf][j] + bv[nf];
            }
        }
    }
}

extern "C" void kernel_launch(void* const* d_in, const int* in_sizes, int n_in,
                              void* d_out, int out_size, void* d_ws, size_t ws_size,
                              hipStream_t stream) {
    const float* x  = (const float*)d_in[0];
    const float* W  = (const float*)d_in[1];
    const float* b  = (const float*)d_in[2];
    const float* Vr = (const float*)d_in[3];
    const float* C  = (const float*)d_in[4];
    float* out = (float*)d_out;

    const int M = in_sizes[0] / DK;        // 65536
    bf16_t* Weff = (bf16_t*)d_ws;          // 1024*1024*2 = 2 MB scratch

    dim3 wgrid(8, 16);
    weff_kernel<<<wgrid, 128, 0, stream>>>(W, Vr, C, Weff);

    const int mtiles = M / BM;             // 512
    const int nwg = mtiles * (DN / BN);    // 4096
    corrlin_gemm_kernel<<<nwg, 256, 0, stream>>>(x, Weff, b, out);
}

// Round 2
// 265.066 us; speedup vs baseline: 2.1079x; 2.1079x over previous
//
#include <hip/hip_runtime.h>
#include <hip/hip_bf16.h>

typedef __bf16 bf16_t;
typedef __bf16 bf16x8 __attribute__((ext_vector_type(8)));
typedef float  f32x4  __attribute__((ext_vector_type(4)));

#define DK 1024   // d_in  (K)
#define DN 1024   // d_out (N)
#define RNK 32
#define BM 128
#define BN 128
#define BK 64
#define NKT (DK / BK)   // 16 K-tiles

// ---- Pass 1: W_eff = W + C @ V_r^T, stored bf16 PRE-SWIZZLED ---------------
// Layout: chunks [bn][kt] of 16KB (bn=n-tile of 128 rows, kt=k-tile of 64).
// Within chunk, element (rloc, kl): byte = rloc*128 + ((kl>>3)*16 ^ ((rloc&7)<<4)) + (kl&7)*2
// == exact LDS image the GEMM's swizzled ds_read_b128 expects, so the GEMM can
// stage it with linear global_load_lds (swizzle-on-source, linear dest).
__global__ void weff_kernel(const float* __restrict__ W,
                            const float* __restrict__ Vr,
                            const float* __restrict__ C,
                            bf16_t* __restrict__ WeffSw)
{
    const int o  = blockIdx.x;       // 0..1023 (d_out row)
    const int g  = threadIdx.x;      // 0..127  (8-wide d_in group)
    const int d0 = g * 8;

    f32x4 cv[8];
#pragma unroll
    for (int q = 0; q < 8; ++q) cv[q] = *(const f32x4*)(C + o * RNK + q * 4);

    const f32x4* wrow = (const f32x4*)(W + (size_t)o * DK + d0);
    f32x4 w0 = wrow[0], w1 = wrow[1];
    float acc[8];
#pragma unroll
    for (int e = 0; e < 4; ++e) { acc[e] = w0[e]; acc[4 + e] = w1[e]; }

#pragma unroll
    for (int e = 0; e < 8; ++e) {
        const f32x4* vre = (const f32x4*)(Vr + (size_t)(d0 + e) * RNK);
        float s = 0.f;
#pragma unroll
        for (int q = 0; q < 8; ++q) {
            f32x4 v = vre[q];
            s += cv[q][0] * v[0] + cv[q][1] * v[1] + cv[q][2] * v[2] + cv[q][3] * v[3];
        }
        acc[e] += s;
    }

    bf16x8 out;
#pragma unroll
    for (int e = 0; e < 8; ++e) out[e] = (bf16_t)acc[e];

    const int bn = o >> 7, rloc = o & 127;
    const int kt = g >> 3, kgrp = g & 7;
    const size_t byte = (size_t)(bn * 16 + kt) * 16384
                      + rloc * 128 + ((kgrp * 16) ^ ((rloc & 7) << 4));
    *(bf16x8*)((char*)WeffSw + byte) = out;
}

// ---- Pass 2: out = x @ Weff^T + b ------------------------------------------
// 128x128 tile, BK=64, 4 waves (2x2 of 64x64), 16x16x32 bf16 MFMA.
// A: reg-staged fp32->bf16 with XOR-swizzled ds_write (T14 early loads).
// B: linear global_load_lds from pre-swizzled Weff chunks.
// Epilogue: LDS transpose -> f32x4 stores, 256B-contiguous row segments.
__global__ __launch_bounds__(256, 2) void corrlin_gemm_kernel(
    const float* __restrict__ X, const bf16_t* __restrict__ WeffSw,
    const float* __restrict__ bias, float* __restrict__ Out)
{
    __shared__ __align__(16) char smem[32768];
    bf16_t* Alds  = (bf16_t*)smem;          // 16KB
    char*   Bldsb = smem + 16384;           // 16KB

    const int tid = threadIdx.x;
    const int nwg = gridDim.x;
    const int b0  = blockIdx.x;
    // XCD-bijective swizzle (nwg % 8 == 0): contiguous logical range per XCD.
    const int L  = (b0 & 7) * (nwg >> 3) + (b0 >> 3);
    const int bm = L >> 3;          // DN/BN == 8
    const int bn = L & 7;
    const int m0 = bm * BM;

    const int lane = tid & 63;
    const int wid  = tid >> 6;
    const int wm   = wid >> 1;      // 0..1
    const int wn   = wid & 1;       // 0..1
    const int srow = tid >> 3;      // 0..31
    const int sseg = tid & 7;       // 0..7

    f32x4 acc[4][4] = {};
    f32x4 a_reg[4][2];

    const size_t chunk0 = (size_t)(bn * 16) * 16384;

    auto load_A = [&](int kt) {
#pragma unroll
        for (int i = 0; i < 4; ++i) {
            const float* pa = X + (size_t)(m0 + i * 32 + srow) * DK + kt * BK + sseg * 8;
            a_reg[i][0] = *(const f32x4*)pa;
            a_reg[i][1] = *(const f32x4*)(pa + 4);
        }
    };
    auto store_A = [&]() {
#pragma unroll
        for (int i = 0; i < 4; ++i) {
            const int row = i * 32 + srow;
            const int off = row * 128 + ((sseg * 16) ^ ((row & 7) << 4));
            bf16x8 av;
#pragma unroll
            for (int j = 0; j < 4; ++j) { av[j] = (bf16_t)a_reg[i][0][j]; av[4 + j] = (bf16_t)a_reg[i][1][j]; }
            *(bf16x8*)((char*)Alds + off) = av;
        }
    };
    auto issue_B = [&](int kt) {
        const char* g = (const char*)WeffSw + chunk0 + (size_t)kt * 16384;
#pragma unroll
        for (int c = 0; c < 4; ++c) {
            const int lin = c * 4096 + wid * 1024;   // wave-uniform LDS base
            __builtin_amdgcn_global_load_lds(
                (const __attribute__((address_space(1))) void*)(g + lin + lane * 16),
                (__attribute__((address_space(3))) void*)(Bldsb + lin),
                16, 0, 0);
        }
    };
    auto compute_tile = [&]() {
#pragma unroll
        for (int ks = 0; ks < 2; ++ks) {
            bf16x8 af[4], bfr[4];
            const int kb = ks * 64 + (lane >> 4) * 16;
#pragma unroll
            for (int mf = 0; mf < 4; ++mf) {
                const int row = wm * 64 + mf * 16 + (lane & 15);
                af[mf] = *(const bf16x8*)((const char*)Alds + row * 128 + (kb ^ ((row & 7) << 4)));
            }
#pragma unroll
            for (int nf = 0; nf < 4; ++nf) {
                const int row = wn * 64 + nf * 16 + (lane & 15);
                bfr[nf] = *(const bf16x8*)((const char*)Bldsb + row * 128 + (kb ^ ((row & 7) << 4)));
            }
#pragma unroll
            for (int mf = 0; mf < 4; ++mf)
#pragma unroll
                for (int nf = 0; nf < 4; ++nf)
                    acc[mf][nf] = __builtin_amdgcn_mfma_f32_16x16x32_bf16(
                        af[mf], bfr[nf], acc[mf][nf], 0, 0, 0);
        }
    };

    // prologue
    issue_B(0);
    load_A(0);
    store_A();
    __syncthreads();            // drains B gloadlds (vmcnt0) + A ds_writes

    for (int kt = 0; kt < NKT - 1; ++kt) {
        load_A(kt + 1);         // early: HBM latency hides under compute
        compute_tile();
        __syncthreads();        // all waves done reading LDS
        issue_B(kt + 1);
        store_A();
        __syncthreads();        // vmcnt0 drain at barrier -> tiles ready
    }
    compute_tile();
    __syncthreads();            // LDS free for epilogue reuse

    // ---- epilogue: transpose through LDS, full-line stores -----------------
    float* tb = (float*)smem + wid * 1280;   // per-wave 16x80 f32 chunk (5KB)
    const int mbase = m0 + wm * 64;
    const int nbase = bn * BN + wn * 64;
    float bv[4];
#pragma unroll
    for (int nf = 0; nf < 4; ++nf) bv[nf] = bias[nbase + nf * 16 + (lane & 15)];

#pragma unroll
    for (int mf = 0; mf < 4; ++mf) {
#pragma unroll
        for (int nf = 0; nf < 4; ++nf)
#pragma unroll
            for (int j = 0; j < 4; ++j) {
                const int r = (lane >> 4) * 4 + j;      // 0..15
                const int c = nf * 16 + (lane & 15);    // 0..63
                tb[r * 80 + c] = acc[mf][nf][j] + bv[nf];
            }
        __syncthreads();
#pragma unroll
        for (int jj = 0; jj < 4; ++jj) {
            const int rr = jj * 4 + (lane >> 4);        // 0..15
            const int cc = (lane & 15) * 4;
            f32x4 v = *(const f32x4*)&tb[rr * 80 + cc];
            // lanes 0-15: one row, 64 consecutive floats = 256B contiguous
            *(f32x4*)&Out[(size_t)(mbase + mf * 16 + rr) * DN + nbase + cc] = v;
        }
        __syncthreads();
    }
}

extern "C" void kernel_launch(void* const* d_in, const int* in_sizes, int n_in,
                              void* d_out, int out_size, void* d_ws, size_t ws_size,
                              hipStream_t stream) {
    const float* x  = (const float*)d_in[0];
    const float* W  = (const float*)d_in[1];
    const float* b  = (const float*)d_in[2];
    const float* Vr = (const float*)d_in[3];
    const float* C  = (const float*)d_in[4];
    float* out = (float*)d_out;

    const int M = in_sizes[0] / DK;            // 65536
    bf16_t* WeffSw = (bf16_t*)d_ws;            // 2 MB pre-swizzled W_eff

    weff_kernel<<<DN, 128, 0, stream>>>(W, Vr, C, WeffSw);

    const int mtiles = M / BM;                 // 512
    const int nwg = mtiles * (DN / BN);        // 4096
    corrlin_gemm_kernel<<<nwg, 256, 0, stream>>>(x, WeffSw, b, out);
}